// Round 3
// baseline (290.992 us; speedup 1.0000x reference)
//
#include <hip/hip_runtime.h>
#include <hip/hip_bf16.h>

// Problem constants (from reference): N=500000, C=128, R=4 (C/R=32), B=32.
#define C 128
#define CR 32
#define B 32

typedef float f32x4 __attribute__((ext_vector_type(4)));   // clang-native vec4

// ---------------------------------------------------------------------------
// Kernel 1: segment sum + counts, float4-vectorized.
// 256 threads = 32 column-groups (float4) x 8 row-lanes. batch is sorted, so
// nearly every block lies inside one segment -> fast path with no per-row
// batch loads and no flush branch; boundary blocks take the checked path.
// Partials flushed with atomicAdd (sums zeroed by memset beforehand).
// ---------------------------------------------------------------------------
__global__ __launch_bounds__(256) void seg_sum_kernel(
    const f32x4* __restrict__ x4, const int* __restrict__ batch,
    float* __restrict__ sums, float* __restrict__ counts,
    int N, int rows_per_block)
{
    const int t  = threadIdx.x;
    const int c4 = t & 31;                 // float4 column group 0..31
    const int rl = t >> 5;                 // row lane 0..7
    const long base = (long)blockIdx.x * rows_per_block;
    long rend = base + rows_per_block;
    if (rend > N) rend = N;
    long r = base + rl;
    if (r >= rend) return;

    f32x4 acc = (f32x4)(0.f, 0.f, 0.f, 0.f);
    int cnt = 0;

    const int segfirst = batch[base];
    const int seglast  = batch[rend - 1];

    if (segfirst == seglast) {
        // fast path: whole block in one segment, pure streaming float4 loads
        #pragma unroll 4
        for (; r < rend; r += 8) {
            f32x4 v = x4[r * 32 + c4];
            acc += v;
            cnt++;
        }
        atomicAdd(&sums[segfirst * C + c4 * 4 + 0], acc.x);
        atomicAdd(&sums[segfirst * C + c4 * 4 + 1], acc.y);
        atomicAdd(&sums[segfirst * C + c4 * 4 + 2], acc.z);
        atomicAdd(&sums[segfirst * C + c4 * 4 + 3], acc.w);
        if (c4 == 0) atomicAdd(&counts[segfirst], (float)cnt);
    } else {
        // boundary block: per-row segment check
        int curseg = batch[r];
        for (; r < rend; r += 8) {
            int b = batch[r];
            if (b != curseg) {
                atomicAdd(&sums[curseg * C + c4 * 4 + 0], acc.x);
                atomicAdd(&sums[curseg * C + c4 * 4 + 1], acc.y);
                atomicAdd(&sums[curseg * C + c4 * 4 + 2], acc.z);
                atomicAdd(&sums[curseg * C + c4 * 4 + 3], acc.w);
                if (c4 == 0) atomicAdd(&counts[curseg], (float)cnt);
                acc = (f32x4)(0.f, 0.f, 0.f, 0.f);
                cnt = 0; curseg = b;
            }
            f32x4 v = x4[r * 32 + c4];
            acc += v;
            cnt++;
        }
        atomicAdd(&sums[curseg * C + c4 * 4 + 0], acc.x);
        atomicAdd(&sums[curseg * C + c4 * 4 + 1], acc.y);
        atomicAdd(&sums[curseg * C + c4 * 4 + 2], acc.z);
        atomicAdd(&sums[curseg * C + c4 * 4 + 3], acc.w);
        if (c4 == 0) atomicAdd(&counts[curseg], (float)cnt);
    }
}

// ---------------------------------------------------------------------------
// Kernel 2: avg = sums/counts; h = relu(avg@W1 + b1); attn = sigmoid(h@W2+b2)
// Single block, 1024 threads. avg and h staged in LDS.
// ---------------------------------------------------------------------------
__global__ __launch_bounds__(1024) void mlp_gate_kernel(
    const float* __restrict__ sums, const float* __restrict__ counts,
    const float* __restrict__ W1, const float* __restrict__ b1,
    const float* __restrict__ W2, const float* __restrict__ b2,
    float* __restrict__ attn)
{
    __shared__ float s_avg[B][C];
    __shared__ float s_h[B][CR];
    const int tid = threadIdx.x;

    for (int k = tid; k < B * C; k += 1024) {
        int g = k >> 7;
        s_avg[g][k & (C - 1)] = sums[k] / fmaxf(counts[g], 1.0f);
    }
    __syncthreads();

    {
        int g = tid >> 5;
        int j = tid & (CR - 1);
        float d = b1[j];
        #pragma unroll 8
        for (int c = 0; c < C; ++c)
            d += s_avg[g][c] * W1[c * CR + j];
        s_h[g][j] = fmaxf(d, 0.0f);
    }
    __syncthreads();

    for (int k = tid; k < B * C; k += 1024) {
        int g = k >> 7;
        int c = k & (C - 1);
        float d = b2[c];
        #pragma unroll
        for (int j = 0; j < CR; ++j)
            d += s_h[g][j] * W2[j * C + c];
        attn[k] = 1.0f / (1.0f + expf(-d));
    }
}

// ---------------------------------------------------------------------------
// Kernel 3: out[n][c] = x[n][c] * attn[batch[n]][c], float4-vectorized.
// Non-temporal stores: keep x L3-resident for its re-read instead of letting
// the 256MB write stream evict it. attn (16KB) is L1-resident.
// ---------------------------------------------------------------------------
__global__ __launch_bounds__(256) void scale_kernel(
    const f32x4* __restrict__ x4, const int* __restrict__ batch,
    const f32x4* __restrict__ attn4, f32x4* __restrict__ out4,
    long total4)
{
    long idx    = (long)blockIdx.x * blockDim.x + threadIdx.x;
    long stride = (long)gridDim.x * blockDim.x;
    for (; idx < total4; idx += stride) {
        long row = idx >> 5;                 // C/4 = 32 float4 per row
        int  c4  = (int)(idx & 31);
        int  b   = batch[row];
        f32x4 xv = x4[idx];
        f32x4 av = attn4[b * 32 + c4];
        f32x4 o  = xv * av;
        __builtin_nontemporal_store(o, &out4[idx]);
    }
}

extern "C" void kernel_launch(void* const* d_in, const int* in_sizes, int n_in,
                              void* d_out, int out_size, void* d_ws, size_t ws_size,
                              hipStream_t stream) {
    const float* x     = (const float*)d_in[0];
    const int*   batch = (const int*)d_in[1];
    // d_in[2] = batch_num scalar (known = 32, compile-time B)
    const float* W1 = (const float*)d_in[3];
    const float* b1 = (const float*)d_in[4];
    const float* W2 = (const float*)d_in[5];
    const float* b2 = (const float*)d_in[6];
    float* out = (float*)d_out;

    const int N = in_sizes[0] / C;

    // workspace layout (floats): sums[B*C]=4096 | counts[B] (padded to 64) | attn[B*C]
    float* sums   = (float*)d_ws;
    float* counts = sums + B * C;          // offset 4096
    float* attn   = counts + 64;           // offset 4160 floats (16B aligned)

    (void)hipMemsetAsync(d_ws, 0, (size_t)(B * C + 64) * sizeof(float), stream);

    const int rows_per_block = 256;
    const int nblocks = (N + rows_per_block - 1) / rows_per_block;
    seg_sum_kernel<<<nblocks, 256, 0, stream>>>((const f32x4*)x, batch,
                                                sums, counts, N, rows_per_block);

    mlp_gate_kernel<<<1, 1024, 0, stream>>>(sums, counts, W1, b1, W2, b2, attn);

    const long total4 = (long)N * (C / 4);
    scale_kernel<<<2048, 256, 0, stream>>>((const f32x4*)x, batch,
                                           (const f32x4*)attn, (f32x4*)out, total4);
}

// Round 4
// 259.522 us; speedup vs baseline: 1.1213x; 1.1213x over previous
//
#include <hip/hip_runtime.h>
#include <hip/hip_bf16.h>

// Problem constants: N=500000, C=128, R=4 (C/R=32), B=32.
#define C 128
#define CR 32
#define B 32
#define RPB 256                       // rows per block in the partial-sum pass

typedef float f32x4 __attribute__((ext_vector_type(4)));

// ---------------------------------------------------------------------------
// Kernel 1: per-block partial sums — NO atomics on the fast path.
// 256 thr = 32 float4-column-groups x 8 row-lanes. Blocks fully inside one
// segment (the overwhelming majority; batch is sorted) accumulate in registers
// (8-deep explicit load pipeline), LDS-reduce the 8 row-lanes, and write one
// partial[block][C] row with plain stores + segid[block]. Boundary blocks
// (~31 of 1954) atomicAdd straight into sums and set segid=-1.
// ---------------------------------------------------------------------------
__global__ __launch_bounds__(256) void seg_partial_kernel(
    const f32x4* __restrict__ x4, const int* __restrict__ batch,
    f32x4* __restrict__ partial4, int* __restrict__ segid,
    float* __restrict__ sums, float* __restrict__ counts, int N)
{
    const int t  = threadIdx.x;
    const int c4 = t & 31;                 // float4 column group 0..31
    const int rl = t >> 5;                 // row lane 0..7
    const long base = (long)blockIdx.x * RPB;
    long rend = base + RPB;
    if (rend > N) rend = N;

    const int segfirst = batch[base];
    const int seglast  = batch[rend - 1];

    if (segfirst == seglast) {
        // ---- fast path: streaming, deeply pipelined, atomic-free ----
        const f32x4* p = x4 + (base + rl) * 32 + c4;
        long r = base + rl;
        f32x4 acc0 = (f32x4)(0.f), acc1 = (f32x4)(0.f);
        f32x4 acc2 = (f32x4)(0.f), acc3 = (f32x4)(0.f);
        while (r + 56 < rend) {            // 8 rows (stride 8) per iteration
            f32x4 v0 = p[0 * 256];
            f32x4 v1 = p[1 * 256];
            f32x4 v2 = p[2 * 256];
            f32x4 v3 = p[3 * 256];
            f32x4 v4 = p[4 * 256];
            f32x4 v5 = p[5 * 256];
            f32x4 v6 = p[6 * 256];
            f32x4 v7 = p[7 * 256];
            acc0 += v0; acc1 += v1; acc2 += v2; acc3 += v3;
            acc0 += v4; acc1 += v5; acc2 += v6; acc3 += v7;
            r += 64; p += 8 * 256;
        }
        while (r < rend) { acc0 += p[0]; r += 8; p += 256; }
        f32x4 acc = (acc0 + acc1) + (acc2 + acc3);

        __shared__ f32x4 s_red[8][32];
        s_red[rl][c4] = acc;
        __syncthreads();
        if (t < 32) {
            f32x4 s = s_red[0][t];
            #pragma unroll
            for (int i = 1; i < 8; ++i) s += s_red[i][t];
            partial4[(long)blockIdx.x * 32 + t] = s;
        }
        if (t == 0) segid[blockIdx.x] = segfirst;
    } else {
        // ---- boundary path (rare): per-row check, atomic flush ----
        long r = base + rl;
        f32x4 acc = (f32x4)(0.f);
        int cnt = 0;
        int curseg = batch[r];
        for (; r < rend; r += 8) {
            int b = batch[r];
            if (b != curseg) {
                atomicAdd(&sums[curseg * C + c4 * 4 + 0], acc.x);
                atomicAdd(&sums[curseg * C + c4 * 4 + 1], acc.y);
                atomicAdd(&sums[curseg * C + c4 * 4 + 2], acc.z);
                atomicAdd(&sums[curseg * C + c4 * 4 + 3], acc.w);
                if (c4 == 0) atomicAdd(&counts[curseg], (float)cnt);
                acc = (f32x4)(0.f);
                cnt = 0; curseg = b;
            }
            acc += x4[r * 32 + c4];
            cnt++;
        }
        atomicAdd(&sums[curseg * C + c4 * 4 + 0], acc.x);
        atomicAdd(&sums[curseg * C + c4 * 4 + 1], acc.y);
        atomicAdd(&sums[curseg * C + c4 * 4 + 2], acc.z);
        atomicAdd(&sums[curseg * C + c4 * 4 + 3], acc.w);
        if (c4 == 0) atomicAdd(&counts[curseg], (float)cnt);
        if (t == 0) segid[blockIdx.x] = -1;
    }
}

// ---------------------------------------------------------------------------
// Kernel 2: fold partials into sums/counts. One block per segment (32 blocks,
// 128 threads = one column each). segid[] is wave-uniform per iteration, so
// the branch is divergence-free; only ~61 of 1954 iterations load data.
// Single writer per address -> plain read-modify-write on top of the
// boundary blocks' atomic contributions.
// ---------------------------------------------------------------------------
__global__ __launch_bounds__(128) void reduce_kernel(
    const float* __restrict__ partial, const int* __restrict__ segid,
    float* __restrict__ sums, float* __restrict__ counts, int nblocks, int N)
{
    const int seg = blockIdx.x;
    const int c   = threadIdx.x;
    float acc = 0.f;
    int cnt = 0;
    for (int blk = 0; blk < nblocks; ++blk) {
        if (segid[blk] == seg) {
            acc += partial[(long)blk * C + c];
            int rows = N - blk * RPB;
            cnt += rows < RPB ? rows : RPB;
        }
    }
    sums[seg * C + c] += acc;
    if (c == 0) counts[seg] += (float)cnt;
}

// ---------------------------------------------------------------------------
// Kernel 3: avg = sums/counts; h = relu(avg@W1+b1); attn = sigmoid(h@W2+b2)
// ---------------------------------------------------------------------------
__global__ __launch_bounds__(1024) void mlp_gate_kernel(
    const float* __restrict__ sums, const float* __restrict__ counts,
    const float* __restrict__ W1, const float* __restrict__ b1,
    const float* __restrict__ W2, const float* __restrict__ b2,
    float* __restrict__ attn)
{
    __shared__ float s_avg[B][C];
    __shared__ float s_h[B][CR];
    const int tid = threadIdx.x;

    for (int k = tid; k < B * C; k += 1024) {
        int g = k >> 7;
        s_avg[g][k & (C - 1)] = sums[k] / fmaxf(counts[g], 1.0f);
    }
    __syncthreads();

    {
        int g = tid >> 5;
        int j = tid & (CR - 1);
        float d = b1[j];
        #pragma unroll 8
        for (int c = 0; c < C; ++c)
            d += s_avg[g][c] * W1[c * CR + j];
        s_h[g][j] = fmaxf(d, 0.0f);
    }
    __syncthreads();

    for (int k = tid; k < B * C; k += 1024) {
        int g = k >> 7;
        int c = k & (C - 1);
        float d = b2[c];
        #pragma unroll
        for (int j = 0; j < CR; ++j)
            d += s_h[g][j] * W2[j * C + c];
        attn[k] = 1.0f / (1.0f + expf(-d));
    }
}

// ---------------------------------------------------------------------------
// Kernel 4: out[n][c] = x[n][c] * attn[batch[n]][c]. NT stores keep x
// L3-resident across replays (replay counters confirmed FETCH ~0).
// ---------------------------------------------------------------------------
__global__ __launch_bounds__(256) void scale_kernel(
    const f32x4* __restrict__ x4, const int* __restrict__ batch,
    const f32x4* __restrict__ attn4, f32x4* __restrict__ out4,
    long total4)
{
    long idx    = (long)blockIdx.x * blockDim.x + threadIdx.x;
    long stride = (long)gridDim.x * blockDim.x;
    for (; idx < total4; idx += stride) {
        long row = idx >> 5;                 // C/4 = 32 float4 per row
        int  c4  = (int)(idx & 31);
        int  b   = batch[row];
        f32x4 xv = x4[idx];
        f32x4 av = attn4[b * 32 + c4];
        f32x4 o  = xv * av;
        __builtin_nontemporal_store(o, &out4[idx]);
    }
}

extern "C" void kernel_launch(void* const* d_in, const int* in_sizes, int n_in,
                              void* d_out, int out_size, void* d_ws, size_t ws_size,
                              hipStream_t stream) {
    const float* x     = (const float*)d_in[0];
    const int*   batch = (const int*)d_in[1];
    // d_in[2] = batch_num scalar (known = 32, compile-time B)
    const float* W1 = (const float*)d_in[3];
    const float* b1 = (const float*)d_in[4];
    const float* W2 = (const float*)d_in[5];
    const float* b2 = (const float*)d_in[6];
    float* out = (float*)d_out;

    const int N = in_sizes[0] / C;
    const int nblocks = (N + RPB - 1) / RPB;

    // ws layout (floats): sums[4096] | counts[64] | attn[4096] | partial[nblocks*128] | segid[nblocks]
    float* sums    = (float*)d_ws;
    float* counts  = sums + B * C;                    // 4096
    float* attn    = counts + 64;                     // 4160
    float* partial = attn + B * C;                    // 8256 (16B-aligned)
    int*   segid   = (int*)(partial + (long)nblocks * C);

    // zero only sums+counts (partial/segid fully overwritten each call)
    (void)hipMemsetAsync(d_ws, 0, (size_t)(B * C + 64) * sizeof(float), stream);

    seg_partial_kernel<<<nblocks, 256, 0, stream>>>((const f32x4*)x, batch,
                                                    (f32x4*)partial, segid,
                                                    sums, counts, N);

    reduce_kernel<<<B, 128, 0, stream>>>(partial, segid, sums, counts, nblocks, N);

    mlp_gate_kernel<<<1, 1024, 0, stream>>>(sums, counts, W1, b1, W2, b2, attn);

    const long total4 = (long)N * (C / 4);
    scale_kernel<<<2048, 256, 0, stream>>>((const f32x4*)x, batch,
                                           (const f32x4*)attn, (f32x4*)out, total4);
}

// Round 5
// 258.205 us; speedup vs baseline: 1.1270x; 1.0051x over previous
//
#include <hip/hip_runtime.h>
#include <hip/hip_bf16.h>

// Problem constants: N=500000, C=128, R=4 (C/R=32), B=32.
#define C 128
#define CR 32
#define B 32
#define RPB 256                       // rows per block in the partial-sum pass

typedef float f32x4 __attribute__((ext_vector_type(4)));

__device__ inline int lower_bound_i(const int* __restrict__ a, int n, int key) {
    int lo = 0, hi = n;
    while (lo < hi) {
        int mid = (lo + hi) >> 1;
        if (a[mid] < key) lo = mid + 1; else hi = mid;
    }
    return lo;
}

// ---------------------------------------------------------------------------
// Kernel 1: per-block partial sums. NO atomics, NO global init required.
// 256 thr = 32 float4-column-groups x 8 row-lanes. Single-segment blocks
// (batch sorted -> all but ~31 of 1954) accumulate with an 8-deep explicit
// load pipeline, LDS-reduce the 8 row-lanes, write partial[block][C] with
// plain stores. Multi-segment blocks exit; reduce_kernel re-reads their rows.
// ---------------------------------------------------------------------------
__global__ __launch_bounds__(256) void seg_partial_kernel(
    const f32x4* __restrict__ x4, const int* __restrict__ batch,
    f32x4* __restrict__ partial4, int N)
{
    const int t  = threadIdx.x;
    const int c4 = t & 31;                 // float4 column group 0..31
    const int rl = t >> 5;                 // row lane 0..7
    const long base = (long)blockIdx.x * RPB;
    long rend = base + RPB;
    if (rend > N) rend = N;

    if (batch[base] != batch[rend - 1]) return;   // boundary block: skip

    const f32x4* p = x4 + (base + rl) * 32 + c4;
    long r = base + rl;
    f32x4 acc0 = (f32x4)(0.f), acc1 = (f32x4)(0.f);
    f32x4 acc2 = (f32x4)(0.f), acc3 = (f32x4)(0.f);
    while (r + 56 < rend) {                // 8 rows (stride 8) per iteration
        f32x4 v0 = p[0 * 256];
        f32x4 v1 = p[1 * 256];
        f32x4 v2 = p[2 * 256];
        f32x4 v3 = p[3 * 256];
        f32x4 v4 = p[4 * 256];
        f32x4 v5 = p[5 * 256];
        f32x4 v6 = p[6 * 256];
        f32x4 v7 = p[7 * 256];
        acc0 += v0; acc1 += v1; acc2 += v2; acc3 += v3;
        acc0 += v4; acc1 += v5; acc2 += v6; acc3 += v7;
        r += 64; p += 8 * 256;
    }
    while (r < rend) { acc0 += p[0]; r += 8; p += 256; }
    f32x4 acc = (acc0 + acc1) + (acc2 + acc3);

    __shared__ f32x4 s_red[8][32];
    s_red[rl][c4] = acc;
    __syncthreads();
    if (t < 32) {
        f32x4 s = s_red[0][t];
        #pragma unroll
        for (int i = 1; i < 8; ++i) s += s_red[i][t];
        partial4[(long)blockIdx.x * 32 + t] = s;
    }
}

// ---------------------------------------------------------------------------
// Kernel 2: one block per segment. Binary-search batch for [lo,hi); sum the
// full blocks' partials + read head/tail rows of x directly. Plain stores.
// counts = hi - lo exactly. Fully deterministic, no init needed.
// ---------------------------------------------------------------------------
__global__ __launch_bounds__(128) void reduce_kernel(
    const float* __restrict__ x, const int* __restrict__ batch,
    const float* __restrict__ partial,
    float* __restrict__ sums, float* __restrict__ counts, int N)
{
    const int seg = blockIdx.x;
    const int c   = threadIdx.x;

    const int lo = lower_bound_i(batch, N, seg);       // uniform (broadcast loads)
    const int hi = lower_bound_i(batch, N, seg + 1);

    float acc = 0.f;
    const int fb0 = (lo + RPB - 1) / RPB;              // first fully-inside block
    const int fb1 = hi / RPB;                          // one past last fully-inside
    if (fb0 < fb1) {
        for (int blk = fb0; blk < fb1; ++blk)
            acc += partial[(long)blk * C + c];         // coalesced 512B rows
        for (long r = lo; r < (long)fb0 * RPB; ++r)    // head rows (<RPB)
            acc += x[r * C + c];
        for (long r = (long)fb1 * RPB; r < hi; ++r)    // tail rows (<RPB)
            acc += x[r * C + c];
    } else {
        for (long r = lo; r < hi; ++r)                 // tiny segment
            acc += x[r * C + c];
    }
    sums[seg * C + c] = acc;
    if (c == 0) counts[seg] = (float)(hi - lo);
}

// ---------------------------------------------------------------------------
// Kernel 3: avg = sums/counts; h = relu(avg@W1+b1); attn = sigmoid(h@W2+b2)
// ---------------------------------------------------------------------------
__global__ __launch_bounds__(1024) void mlp_gate_kernel(
    const float* __restrict__ sums, const float* __restrict__ counts,
    const float* __restrict__ W1, const float* __restrict__ b1,
    const float* __restrict__ W2, const float* __restrict__ b2,
    float* __restrict__ attn)
{
    __shared__ float s_avg[B][C];
    __shared__ float s_h[B][CR];
    const int tid = threadIdx.x;

    for (int k = tid; k < B * C; k += 1024) {
        int g = k >> 7;
        s_avg[g][k & (C - 1)] = sums[k] / fmaxf(counts[g], 1.0f);
    }
    __syncthreads();

    {
        int g = tid >> 5;
        int j = tid & (CR - 1);
        float d = b1[j];
        #pragma unroll 8
        for (int c = 0; c < C; ++c)
            d += s_avg[g][c] * W1[c * CR + j];
        s_h[g][j] = fmaxf(d, 0.0f);
    }
    __syncthreads();

    for (int k = tid; k < B * C; k += 1024) {
        int g = k >> 7;
        int c = k & (C - 1);
        float d = b2[c];
        #pragma unroll
        for (int j = 0; j < CR; ++j)
            d += s_h[g][j] * W2[j * C + c];
        attn[k] = 1.0f / (1.0f + expf(-d));
    }
}

// ---------------------------------------------------------------------------
// Kernel 4: out[n][c] = x[n][c] * attn[batch[n]][c]. NT stores keep x
// L3-resident (x is 244 MiB vs 256 MiB L3) across the graph replays.
// ---------------------------------------------------------------------------
__global__ __launch_bounds__(256) void scale_kernel(
    const f32x4* __restrict__ x4, const int* __restrict__ batch,
    const f32x4* __restrict__ attn4, f32x4* __restrict__ out4,
    long total4)
{
    long idx    = (long)blockIdx.x * blockDim.x + threadIdx.x;
    long stride = (long)gridDim.x * blockDim.x;
    for (; idx < total4; idx += stride) {
        long row = idx >> 5;                 // C/4 = 32 float4 per row
        int  c4  = (int)(idx & 31);
        int  b   = batch[row];
        f32x4 xv = x4[idx];
        f32x4 av = attn4[b * 32 + c4];
        f32x4 o  = xv * av;
        __builtin_nontemporal_store(o, &out4[idx]);
    }
}

extern "C" void kernel_launch(void* const* d_in, const int* in_sizes, int n_in,
                              void* d_out, int out_size, void* d_ws, size_t ws_size,
                              hipStream_t stream) {
    const float* x     = (const float*)d_in[0];
    const int*   batch = (const int*)d_in[1];
    // d_in[2] = batch_num scalar (known = 32, compile-time B)
    const float* W1 = (const float*)d_in[3];
    const float* b1 = (const float*)d_in[4];
    const float* W2 = (const float*)d_in[5];
    const float* b2 = (const float*)d_in[6];
    float* out = (float*)d_out;

    const int N = in_sizes[0] / C;
    const int nblocks = (N + RPB - 1) / RPB;

    // ws layout (floats): sums[4096] | counts[64] | attn[4096] | partial[nblocks*128]
    float* sums    = (float*)d_ws;
    float* counts  = sums + B * C;                    // 4096
    float* attn    = counts + 64;                     // 4160
    float* partial = attn + B * C;                    // 8256 (16B-aligned)

    seg_partial_kernel<<<nblocks, 256, 0, stream>>>((const f32x4*)x, batch,
                                                    (f32x4*)partial, N);

    reduce_kernel<<<B, 128, 0, stream>>>(x, batch, partial, sums, counts, N);

    mlp_gate_kernel<<<1, 1024, 0, stream>>>(sums, counts, W1, b1, W2, b2, attn);

    const long total4 = (long)N * (C / 4);
    scale_kernel<<<2048, 256, 0, stream>>>((const f32x4*)x, batch,
                                           (const f32x4*)attn, (f32x4*)out, total4);
}

// Round 6
// 151.035 us; speedup vs baseline: 1.9267x; 1.7096x over previous
//
#include <hip/hip_runtime.h>
#include <hip/hip_bf16.h>

// Problem constants: N=500000, C=128, R=4 (C/R=32), B=32.
#define C 128
#define CR 32
#define B 32
#define RPB 256                       // rows per block in the partial-sum pass

typedef float f32x4 __attribute__((ext_vector_type(4)));

__device__ inline int lower_bound_i(const int* __restrict__ a, int n, int key) {
    int lo = 0, hi = n;
    while (lo < hi) {
        int mid = (lo + hi) >> 1;
        if (a[mid] < key) lo = mid + 1; else hi = mid;
    }
    return lo;
}

// ---------------------------------------------------------------------------
// Kernel 1: per-block partial sums. NO atomics, NO global init required.
// 256 thr = 32 float4-column-groups x 8 row-lanes. Single-segment blocks
// (batch sorted -> all but ~31 of 1954) accumulate with an 8-deep explicit
// load pipeline, LDS-reduce the 8 row-lanes, write partial[block][C] with
// plain stores. Multi-segment blocks exit; reduce_kernel re-reads their rows.
// ---------------------------------------------------------------------------
__global__ __launch_bounds__(256) void seg_partial_kernel(
    const f32x4* __restrict__ x4, const int* __restrict__ batch,
    f32x4* __restrict__ partial4, int N)
{
    const int t  = threadIdx.x;
    const int c4 = t & 31;                 // float4 column group 0..31
    const int rl = t >> 5;                 // row lane 0..7
    const long base = (long)blockIdx.x * RPB;
    long rend = base + RPB;
    if (rend > N) rend = N;

    if (batch[base] != batch[rend - 1]) return;   // boundary block: skip

    const f32x4* p = x4 + (base + rl) * 32 + c4;
    long r = base + rl;
    f32x4 acc0 = (f32x4)(0.f), acc1 = (f32x4)(0.f);
    f32x4 acc2 = (f32x4)(0.f), acc3 = (f32x4)(0.f);
    while (r + 56 < rend) {                // 8 rows (stride 8) per iteration
        f32x4 v0 = p[0 * 256];
        f32x4 v1 = p[1 * 256];
        f32x4 v2 = p[2 * 256];
        f32x4 v3 = p[3 * 256];
        f32x4 v4 = p[4 * 256];
        f32x4 v5 = p[5 * 256];
        f32x4 v6 = p[6 * 256];
        f32x4 v7 = p[7 * 256];
        acc0 += v0; acc1 += v1; acc2 += v2; acc3 += v3;
        acc0 += v4; acc1 += v5; acc2 += v6; acc3 += v7;
        r += 64; p += 8 * 256;
    }
    while (r < rend) { acc0 += p[0]; r += 8; p += 256; }
    f32x4 acc = (acc0 + acc1) + (acc2 + acc3);

    __shared__ f32x4 s_red[8][32];
    s_red[rl][c4] = acc;
    __syncthreads();
    if (t < 32) {
        f32x4 s = s_red[0][t];
        #pragma unroll
        for (int i = 1; i < 8; ++i) s += s_red[i][t];
        partial4[(long)blockIdx.x * 32 + t] = s;
    }
}

// ---------------------------------------------------------------------------
// Kernel 2: one block per segment, 1024 threads = 8 row-lanes x 128 cols.
// Binary-search batch for [lo,hi); sum full-block partials + head/tail rows
// of x, all strided over the 8 row-lanes (independent pipelined loads), then
// LDS-reduce. Plain stores; counts = hi - lo exactly. Deterministic, no init.
// ---------------------------------------------------------------------------
__global__ __launch_bounds__(1024) void reduce_kernel(
    const float* __restrict__ x, const int* __restrict__ batch,
    const float* __restrict__ partial,
    float* __restrict__ sums, float* __restrict__ counts, int N)
{
    const int seg = blockIdx.x;
    const int t   = threadIdx.x;
    const int c   = t & (C - 1);           // column 0..127
    const int rl  = t >> 7;                // row lane 0..7

    const int lo = lower_bound_i(batch, N, seg);       // uniform (broadcast)
    const int hi = lower_bound_i(batch, N, seg + 1);

    float acc = 0.f;
    const int fb0 = (lo + RPB - 1) / RPB;              // first fully-inside block
    const int fb1 = hi / RPB;                          // one past last fully-inside
    if (fb0 < fb1) {
        #pragma unroll 4
        for (int blk = fb0 + rl; blk < fb1; blk += 8)  // ~61/8 iters, coalesced
            acc += partial[(long)blk * C + c];
        #pragma unroll 4
        for (long r = lo + rl; r < (long)fb0 * RPB; r += 8)   // head (<RPB rows)
            acc += x[r * C + c];
        #pragma unroll 4
        for (long r = (long)fb1 * RPB + rl; r < hi; r += 8)   // tail (<RPB rows)
            acc += x[r * C + c];
    } else {
        #pragma unroll 4
        for (long r = lo + rl; r < hi; r += 8)         // tiny segment
            acc += x[r * C + c];
    }

    __shared__ float s_red[8][C];
    s_red[rl][c] = acc;
    __syncthreads();
    if (t < C) {
        float s = s_red[0][t];
        #pragma unroll
        for (int i = 1; i < 8; ++i) s += s_red[i][t];
        sums[seg * C + t] = s;
    }
    if (t == 0) counts[seg] = (float)(hi - lo);
}

// ---------------------------------------------------------------------------
// Kernel 3: avg = sums/counts; h = relu(avg@W1+b1); attn = sigmoid(h@W2+b2)
// ---------------------------------------------------------------------------
__global__ __launch_bounds__(1024) void mlp_gate_kernel(
    const float* __restrict__ sums, const float* __restrict__ counts,
    const float* __restrict__ W1, const float* __restrict__ b1,
    const float* __restrict__ W2, const float* __restrict__ b2,
    float* __restrict__ attn)
{
    __shared__ float s_avg[B][C];
    __shared__ float s_h[B][CR];
    const int tid = threadIdx.x;

    for (int k = tid; k < B * C; k += 1024) {
        int g = k >> 7;
        s_avg[g][k & (C - 1)] = sums[k] / fmaxf(counts[g], 1.0f);
    }
    __syncthreads();

    {
        int g = tid >> 5;
        int j = tid & (CR - 1);
        float d = b1[j];
        #pragma unroll 8
        for (int c = 0; c < C; ++c)
            d += s_avg[g][c] * W1[c * CR + j];
        s_h[g][j] = fmaxf(d, 0.0f);
    }
    __syncthreads();

    for (int k = tid; k < B * C; k += 1024) {
        int g = k >> 7;
        int c = k & (C - 1);
        float d = b2[c];
        #pragma unroll
        for (int j = 0; j < CR; ++j)
            d += s_h[g][j] * W2[j * C + c];
        attn[k] = 1.0f / (1.0f + expf(-d));
    }
}

// ---------------------------------------------------------------------------
// Kernel 4: out[n][c] = x[n][c] * attn[batch[n]][c]. NT stores keep x
// L3-resident (x is 244 MiB vs 256 MiB L3) across the graph replays.
// ---------------------------------------------------------------------------
__global__ __launch_bounds__(256) void scale_kernel(
    const f32x4* __restrict__ x4, const int* __restrict__ batch,
    const f32x4* __restrict__ attn4, f32x4* __restrict__ out4,
    long total4)
{
    long idx    = (long)blockIdx.x * blockDim.x + threadIdx.x;
    long stride = (long)gridDim.x * blockDim.x;
    for (; idx < total4; idx += stride) {
        long row = idx >> 5;                 // C/4 = 32 float4 per row
        int  c4  = (int)(idx & 31);
        int  b   = batch[row];
        f32x4 xv = x4[idx];
        f32x4 av = attn4[b * 32 + c4];
        f32x4 o  = xv * av;
        __builtin_nontemporal_store(o, &out4[idx]);
    }
}

extern "C" void kernel_launch(void* const* d_in, const int* in_sizes, int n_in,
                              void* d_out, int out_size, void* d_ws, size_t ws_size,
                              hipStream_t stream) {
    const float* x     = (const float*)d_in[0];
    const int*   batch = (const int*)d_in[1];
    // d_in[2] = batch_num scalar (known = 32, compile-time B)
    const float* W1 = (const float*)d_in[3];
    const float* b1 = (const float*)d_in[4];
    const float* W2 = (const float*)d_in[5];
    const float* b2 = (const float*)d_in[6];
    float* out = (float*)d_out;

    const int N = in_sizes[0] / C;
    const int nblocks = (N + RPB - 1) / RPB;

    // ws layout (floats): sums[4096] | counts[64] | attn[4096] | partial[nblocks*128]
    float* sums    = (float*)d_ws;
    float* counts  = sums + B * C;                    // 4096
    float* attn    = counts + 64;                     // 4160
    float* partial = attn + B * C;                    // 8256 (16B-aligned)

    seg_partial_kernel<<<nblocks, 256, 0, stream>>>((const f32x4*)x, batch,
                                                    (f32x4*)partial, N);

    reduce_kernel<<<B, 1024, 0, stream>>>(x, batch, partial, sums, counts, N);

    mlp_gate_kernel<<<1, 1024, 0, stream>>>(sums, counts, W1, b1, W2, b2, attn);

    const long total4 = (long)N * (C / 4);
    scale_kernel<<<2048, 256, 0, stream>>>((const f32x4*)x, batch,
                                           (const f32x4*)attn, (f32x4*)out, total4);
}

// Round 7
// 134.193 us; speedup vs baseline: 2.1685x; 1.1255x over previous
//
#include <hip/hip_runtime.h>
#include <hip/hip_bf16.h>

// Problem constants: N=500000, C=128, R=4 (C/R=32), B=32.
#define C 128
#define CR 32
#define B 32
#define RPB 256                       // rows per block in the partial-sum pass

typedef float f32x4 __attribute__((ext_vector_type(4)));

__device__ inline int lower_bound_i(const int* __restrict__ a, int n, int key) {
    int lo = 0, hi = n;
    while (lo < hi) {
        int mid = (lo + hi) >> 1;
        if (a[mid] < key) lo = mid + 1; else hi = mid;
    }
    return lo;
}

// ---------------------------------------------------------------------------
// Kernel 1: per-block partial sums. NO atomics, NO global init required.
// 256 thr = 32 float4-column-groups x 8 row-lanes. Single-segment blocks
// (batch sorted -> all but ~31 of 1954) accumulate with an 8-deep explicit
// load pipeline, LDS-reduce the 8 row-lanes, write partial[block][C] with
// plain stores. Multi-segment blocks exit; kernel 2 re-reads their rows.
// ---------------------------------------------------------------------------
__global__ __launch_bounds__(256) void seg_partial_kernel(
    const f32x4* __restrict__ x4, const int* __restrict__ batch,
    f32x4* __restrict__ partial4, int N)
{
    const int t  = threadIdx.x;
    const int c4 = t & 31;                 // float4 column group 0..31
    const int rl = t >> 5;                 // row lane 0..7
    const long base = (long)blockIdx.x * RPB;
    long rend = base + RPB;
    if (rend > N) rend = N;

    if (batch[base] != batch[rend - 1]) return;   // boundary block: skip

    const f32x4* p = x4 + (base + rl) * 32 + c4;
    long r = base + rl;
    f32x4 acc0 = (f32x4)(0.f), acc1 = (f32x4)(0.f);
    f32x4 acc2 = (f32x4)(0.f), acc3 = (f32x4)(0.f);
    while (r + 56 < rend) {                // 8 rows (stride 8) per iteration
        f32x4 v0 = p[0 * 256];
        f32x4 v1 = p[1 * 256];
        f32x4 v2 = p[2 * 256];
        f32x4 v3 = p[3 * 256];
        f32x4 v4 = p[4 * 256];
        f32x4 v5 = p[5 * 256];
        f32x4 v6 = p[6 * 256];
        f32x4 v7 = p[7 * 256];
        acc0 += v0; acc1 += v1; acc2 += v2; acc3 += v3;
        acc0 += v4; acc1 += v5; acc2 += v6; acc3 += v7;
        r += 64; p += 8 * 256;
    }
    while (r < rend) { acc0 += p[0]; r += 8; p += 256; }
    f32x4 acc = (acc0 + acc1) + (acc2 + acc3);

    __shared__ f32x4 s_red[8][32];
    s_red[rl][c4] = acc;
    __syncthreads();
    if (t < 32) {
        f32x4 s = s_red[0][t];
        #pragma unroll
        for (int i = 1; i < 8; ++i) s += s_red[i][t];
        partial4[(long)blockIdx.x * 32 + t] = s;
    }
}

// ---------------------------------------------------------------------------
// Kernel 2: one block per segment, 1024 thr = 32 f32x4-col-groups x 32
// row-lanes. Binary-search batch for [lo,hi); fold full-block partials +
// head/tail rows of x (vectorized, 32-lane-strided -> <=16 pipelined loads),
// LDS-reduce, then compute the MLP gate IN-BLOCK (it only needs this
// segment's avg): h = relu(avg@W1+b1), attn = sigmoid(h@W2+b2).
// Plain stores, deterministic, no init needed. Removes the mlp kernel.
// ---------------------------------------------------------------------------
__global__ __launch_bounds__(1024) void reduce_mlp_kernel(
    const f32x4* __restrict__ x4, const int* __restrict__ batch,
    const f32x4* __restrict__ partial4,
    const float* __restrict__ W1, const float* __restrict__ b1,
    const float* __restrict__ W2, const float* __restrict__ b2,
    float* __restrict__ attn, int N)
{
    const int seg = blockIdx.x;
    const int t   = threadIdx.x;
    const int c4  = t & 31;                // float4 column group 0..31
    const int rl  = t >> 5;                // row lane 0..31

    const int lo = lower_bound_i(batch, N, seg);       // uniform (broadcast)
    const int hi = lower_bound_i(batch, N, seg + 1);

    f32x4 acc = (f32x4)(0.f);
    const int fb0 = (lo + RPB - 1) / RPB;              // first fully-inside block
    const int fb1 = hi / RPB;                          // one past last fully-inside
    if (fb0 < fb1) {
        for (int blk = fb0 + rl; blk < fb1; blk += 32)         // ~61/32 iters
            acc += partial4[(long)blk * 32 + c4];
        #pragma unroll 4
        for (long r = lo + rl; r < (long)fb0 * RPB; r += 32)   // head (<RPB rows)
            acc += x4[r * 32 + c4];
        #pragma unroll 4
        for (long r = (long)fb1 * RPB + rl; r < hi; r += 32)   // tail (<RPB rows)
            acc += x4[r * 32 + c4];
    } else {
        #pragma unroll 4
        for (long r = lo + rl; r < hi; r += 32)                // tiny segment
            acc += x4[r * 32 + c4];
    }

    __shared__ f32x4 s_red[32][32];
    __shared__ float s_avg[C];
    __shared__ float s_h[CR];
    s_red[rl][c4] = acc;
    __syncthreads();
    if (t < 32) {
        f32x4 s = s_red[0][t];
        #pragma unroll
        for (int i = 1; i < 32; ++i) s += s_red[i][t];
        float inv = 1.0f / fmaxf((float)(hi - lo), 1.0f);
        s_avg[4 * t + 0] = s.x * inv;
        s_avg[4 * t + 1] = s.y * inv;
        s_avg[4 * t + 2] = s.z * inv;
        s_avg[4 * t + 3] = s.w * inv;
    }
    __syncthreads();
    if (t < CR) {                           // h = relu(avg @ W1 + b1)
        float d = b1[t];
        #pragma unroll 8
        for (int c = 0; c < C; ++c)
            d += s_avg[c] * W1[c * CR + t]; // W1 row: 32 consecutive -> coalesced
        s_h[t] = fmaxf(d, 0.f);
    }
    __syncthreads();
    if (t < C) {                            // attn = sigmoid(h @ W2 + b2)
        float d = b2[t];
        #pragma unroll
        for (int j = 0; j < CR; ++j)
            d += s_h[j] * W2[j * C + t];    // W2 row: 128 consecutive -> coalesced
        attn[seg * C + t] = 1.0f / (1.0f + expf(-d));
    }
}

// ---------------------------------------------------------------------------
// Kernel 3: out[n][c] = x[n][c] * attn[batch[n]][c]. NT stores keep out from
// polluting L3 so x (244 MiB) stays L3-resident across replays (replay
// counters: FETCH ~33 MB). attn (16KB) is L1-resident.
// ---------------------------------------------------------------------------
__global__ __launch_bounds__(256) void scale_kernel(
    const f32x4* __restrict__ x4, const int* __restrict__ batch,
    const f32x4* __restrict__ attn4, f32x4* __restrict__ out4,
    long total4)
{
    long idx    = (long)blockIdx.x * blockDim.x + threadIdx.x;
    long stride = (long)gridDim.x * blockDim.x;
    for (; idx < total4; idx += stride) {
        long row = idx >> 5;                 // C/4 = 32 float4 per row
        int  c4  = (int)(idx & 31);
        int  b   = batch[row];
        f32x4 xv = x4[idx];
        f32x4 av = attn4[b * 32 + c4];
        f32x4 o  = xv * av;
        __builtin_nontemporal_store(o, &out4[idx]);
    }
}

extern "C" void kernel_launch(void* const* d_in, const int* in_sizes, int n_in,
                              void* d_out, int out_size, void* d_ws, size_t ws_size,
                              hipStream_t stream) {
    const float* x     = (const float*)d_in[0];
    const int*   batch = (const int*)d_in[1];
    // d_in[2] = batch_num scalar (known = 32, compile-time B)
    const float* W1 = (const float*)d_in[3];
    const float* b1 = (const float*)d_in[4];
    const float* W2 = (const float*)d_in[5];
    const float* b2 = (const float*)d_in[6];
    float* out = (float*)d_out;

    const int N = in_sizes[0] / C;
    const int nblocks = (N + RPB - 1) / RPB;

    // ws layout (floats): attn[B*C] | partial[nblocks*C]
    float* attn    = (float*)d_ws;
    float* partial = attn + B * C;                    // 4096 floats in (16B aligned)

    seg_partial_kernel<<<nblocks, 256, 0, stream>>>((const f32x4*)x, batch,
                                                    (f32x4*)partial, N);

    reduce_mlp_kernel<<<B, 1024, 0, stream>>>((const f32x4*)x, batch,
                                              (const f32x4*)partial,
                                              W1, b1, W2, b2, attn, N);

    const long total4 = (long)N * (C / 4);
    scale_kernel<<<2048, 256, 0, stream>>>((const f32x4*)x, batch,
                                           (const f32x4*)attn, (f32x4*)out, total4);
}